// Round 13
// baseline (611.496 us; speedup 1.0000x reference)
//
#include <hip/hip_runtime.h>
#include <math.h>

#define BATCH 8192
#define DIM 1024
#define KDIM 512
#define ALPHA_C 0.1f
#define N_ITERS 50
#define ROWS 32
#define ZSH 512
#define HC 2  // kk-slices of H cached in LDS (of 16)

typedef short bf16x8 __attribute__((ext_vector_type(8)));
typedef float f32x4 __attribute__((ext_vector_type(4)));

__device__ __forceinline__ short f2bf(float x) {
  union { float f; unsigned u; } v; v.f = x;
  unsigned r = v.u + 0x7fffu + ((v.u >> 16) & 1u);
  return (short)(r >> 16);
}
__device__ __forceinline__ float bf2f(short s) {
  union { float f; unsigned u; } v;
  v.u = ((unsigned)(unsigned short)s) << 16;
  return v.f;
}

// XOR-swizzled LDS addressing (16B granule), key = row&15 so that the 4 rows
// written per Z-update instruction (row = rf*16 + lq*4 + e, lq=0..3) land in
// 4 DISTINCT slots (old row&7 key left rows {e,8+e} colliding -> 4-way write
// conflict, 2.9e7 conflict cycles in R9).
__device__ __forceinline__ int zswz(int row, int col) {
  return row * ZSH + ((((col >> 3) ^ (row & 15)) << 3) | (col & 7));
}
__device__ __forceinline__ int zoff8(int row, int colg) {
  return row * ZSH + ((colg ^ (row & 15)) << 3);
}

// ---------------- K1: C = scale * A^T B (C: 512x512 fp32) ------------------
// 64x64 tile, 4x4 per thread, float4 loads (R9 k_mmT was 2x2/float2 with
// 1 wave/SIMD -> latency-bound; this has 2x fewer load instrs, 4x ILP).
__global__ __launch_bounds__(256) void k_mmT(const float* __restrict__ A,
                                             const float* __restrict__ B,
                                             float* __restrict__ C, int K,
                                             float scale) {
  int tx = threadIdx.x & 15;
  int ty = threadIdx.x >> 4;
  int a0 = blockIdx.y * 64 + ty * 4;
  int b0 = blockIdx.x * 64 + tx * 4;
  float acc[4][4] = {};
#pragma unroll 4
  for (int d = 0; d < K; ++d) {
    float4 av = *(const float4*)&A[(size_t)d * KDIM + a0];
    float4 bv = *(const float4*)&B[(size_t)d * KDIM + b0];
    float aa[4] = {av.x, av.y, av.z, av.w};
    float bb[4] = {bv.x, bv.y, bv.z, bv.w};
#pragma unroll
    for (int i = 0; i < 4; ++i)
#pragma unroll
      for (int j = 0; j < 4; ++j) acc[i][j] += aa[i] * bb[j];
  }
#pragma unroll
  for (int i = 0; i < 4; ++i) {
    float4 o = make_float4(acc[i][0] * scale, acc[i][1] * scale,
                           acc[i][2] * scale, acc[i][3] * scale);
    *(float4*)&C[(size_t)(a0 + i) * KDIM + b0] = o;
  }
}

// ---------------- K2: v = dir(G8s·G8s·G4s·1) == dir(G^20·1) (scales cancel);
// L = Rayleigh(G, v). Norm/Rayleigh accumulate in double (overflow-proof).
__global__ __launch_bounds__(1024) void k_power_fast(
    const float* __restrict__ G4, const float* __restrict__ G8,
    const float* __restrict__ G, float* __restrict__ scal) {
  __shared__ float v[KDIM];
  __shared__ float part[1024];
  __shared__ double red[16];
  __shared__ double red2[16];
  __shared__ float stot;
  int tid = threadIdx.x;
  int lane = tid & 63, wid = tid >> 6;
  int col = tid & 511, h = tid >> 9;
  if (h == 0) v[col] = 1.0f;
  __syncthreads();

  const float* mats[3] = {G4, G8, G8};
#pragma unroll
  for (int s = 0; s < 3; ++s) {
    const float* gp = mats[s] + (size_t)(h * 256) * KDIM + col;
    const float* vp = v + h * 256;
    float a0 = 0.f, a1 = 0.f, a2 = 0.f, a3 = 0.f;
#pragma unroll 4
    for (int j = 0; j < 256; j += 4) {
      a0 += gp[(size_t)(j + 0) * KDIM] * vp[j + 0];
      a1 += gp[(size_t)(j + 1) * KDIM] * vp[j + 1];
      a2 += gp[(size_t)(j + 2) * KDIM] * vp[j + 2];
      a3 += gp[(size_t)(j + 3) * KDIM] * vp[j + 3];
    }
    part[tid] = (a0 + a1) + (a2 + a3);
    __syncthreads();
    float u = 0.f;
    double ssq = 0.0;
    if (h == 0) {
      u = part[col] + part[col + 512];
      ssq = (double)u * (double)u;
    }
#pragma unroll
    for (int off = 32; off; off >>= 1) ssq += __shfl_xor(ssq, off);
    if (lane == 0) red[wid] = ssq;
    __syncthreads();
    if (tid == 0) {
      double t = 0.0;
      for (int i = 0; i < 16; ++i) t += red[i];
      stot = (float)(sqrt(t) + 1e-12);
    }
    __syncthreads();
    if (h == 0) v[col] = u / stot;
    __syncthreads();
  }

  // Rayleigh on fp32 G (unscaled)
  {
    const float* gp = G + (size_t)(h * 256) * KDIM + col;
    const float* vp = v + h * 256;
    float a0 = 0.f, a1 = 0.f, a2 = 0.f, a3 = 0.f;
#pragma unroll 4
    for (int j = 0; j < 256; j += 4) {
      a0 += gp[(size_t)(j + 0) * KDIM] * vp[j + 0];
      a1 += gp[(size_t)(j + 1) * KDIM] * vp[j + 1];
      a2 += gp[(size_t)(j + 2) * KDIM] * vp[j + 2];
      a3 += gp[(size_t)(j + 3) * KDIM] * vp[j + 3];
    }
    part[tid] = (a0 + a1) + (a2 + a3);
    __syncthreads();
    double nu = 0.0, de = 0.0;
    if (h == 0) {
      float u = part[col] + part[col + 512];
      nu = (double)v[col] * (double)u;
      de = (double)v[col] * (double)v[col];
    }
#pragma unroll
    for (int off = 32; off; off >>= 1) {
      nu += __shfl_xor(nu, off);
      de += __shfl_xor(de, off);
    }
    if (lane == 0) { red[wid] = nu; red2[wid] = de; }
    __syncthreads();
    if (tid == 0) {
      double n = 0.0, d = 0.0;
      for (int i = 0; i < 16; ++i) { n += red[i]; d += red2[i]; }
      float L = (float)(n / (d + 1e-12));
      float step = 1.0f / L;
      scal[0] = step;
      scal[1] = step * ALPHA_C;
    }
  }
}

// ---------------- K3: pack H = I - step*G (bf16 hi only, B-frag layout) ----
__global__ __launch_bounds__(256) void k_pack_h(const float* __restrict__ G,
                                                const float* __restrict__ scal,
                                                short* __restrict__ Hh) {
  int t = blockIdx.x * 256 + threadIdx.x;  // 512*512
  int k = t >> 9, n = t & 511;
  float step = scal[0];
  float h = ((k == n) ? 1.0f : 0.0f) - step * G[k * KDIM + n];
  int kk = k >> 5, q = (k >> 3) & 3, j = k & 7;
  Hh[((size_t)((kk * 4 + q) * 512 + n)) * 8 + j] = f2bf(h);
}

// Wph[((kk*4+q)*512 + n)*8 + j] = bf16(step*Wd[kk*32+q*8+j][n])
__global__ __launch_bounds__(256) void k_pack_w(const float* __restrict__ Wd,
                                                const float* __restrict__ scal,
                                                short* __restrict__ Wh) {
  int t = blockIdx.x * 256 + threadIdx.x;  // 1024*512
  int k = t >> 9, n = t & 511;
  float w = scal[0] * Wd[k * KDIM + n];
  int kk = k >> 5, q = (k >> 3) & 3, j = k & 7;
  Wh[((size_t)((kk * 4 + q) * 512 + n)) * 8 + j] = f2bf(w);
}

// Wth[((kk*4+q)*1024 + n)*8 + j] = bf16(Wd[n][kk*32+q*8+j])
__global__ __launch_bounds__(256) void k_pack_wt(const float* __restrict__ Wd,
                                                 short* __restrict__ Wh) {
  int t = blockIdx.x * 256 + threadIdx.x;  // 512*1024
  int k = t >> 10, n = t & 1023;
  float w = Wd[n * KDIM + k];
  int kk = k >> 5, q = (k >> 3) & 3, j = k & 7;
  Wh[((size_t)((kk * 4 + q) * 1024 + n)) * 8 + j] = f2bf(w);
}

// ---------------- K4: fused ISTA: 32 rows/block, 256 blocks, 16 waves ------
// R9 + three changes: (1) Z double-buffered -> ONE barrier/iter (R5-proven),
// (2) swizzle key row&15 (kills 4-way write conflicts), (3) first HC kk-slices
// of H cached in LDS (-12.5% L2 stream). LDS = 64 (Z dbuf) + 64 (H) = 128 KB.
// it-rotated kk defeats LICM hoist-and-spill (R4 pathology).
__global__ __launch_bounds__(1024) void k_ista(
    const float* __restrict__ zex, const short* __restrict__ Hh,
    const short* __restrict__ Wph, const short* __restrict__ Wth,
    const float* __restrict__ scal, float* __restrict__ out,
    int* __restrict__ gcnt) {
  __shared__ short Zb[2][ROWS * ZSH];  // 2 x 32 KB
  __shared__ short Hl2[HC * 16384];    // 64 KB: Hh[0 .. HC*16384)
  int tid = threadIdx.x;
  int lane = tid & 63, wid = tid >> 6;  // 16 waves, each 32 cols
  int l15 = lane & 15, lq = lane >> 4;
  int rb = blockIdx.x * ROWS;
  float thr = scal[1];

  // ---------- stage 1: cs = step * X * Wd  (X = permuted zex) ----------
  // X-hi -> Zb[0], X-lo -> Zb[1] in one staging pass per 512-col half.
  f32x4 cs[2][2];
#pragma unroll
  for (int rf = 0; rf < 2; ++rf)
#pragma unroll
    for (int cf = 0; cf < 2; ++cf) cs[rf][cf] = (f32x4){0.f, 0.f, 0.f, 0.f};

  int sr = tid >> 5;         // row 0..31
  int sc = (tid & 31) >> 1;  // col-group 0..15
  int ph = tid & 1;          // m-phase 0..1
  for (int half = 0; half < 2; ++half) {
    __syncthreads();
    {
      const float* src =
          &zex[(size_t)(rb + sr) * DIM + sc * 64 + half * 32 + ph * 16];
#pragma unroll
      for (int m = 0; m < 16; m += 4) {
        float4 xv = *(const float4*)&src[m];
        float xs[4] = {xv.x, xv.y, xv.z, xv.w};
#pragma unroll
        for (int e = 0; e < 4; ++e) {
          int mm = ph * 16 + m + e;
          int dd = ((mm >> 3) << 7) + ((mm & 7) << 4) + sc;
          short hi = f2bf(xs[e]);
          short lo = f2bf(xs[e] - bf2f(hi));
          int zi = zswz(sr, dd);
          Zb[0][zi] = hi;
          Zb[1][zi] = lo;
        }
      }
    }
    __syncthreads();
#pragma unroll 2
    for (int kk = 0; kk < 16; ++kk) {
      int kkg = half * 16 + kk;
      bf16x8 ah[2], al[2];
#pragma unroll
      for (int rf = 0; rf < 2; ++rf) {
        int zo = zoff8(rf * 16 + l15, kk * 4 + lq);
        ah[rf] = *(const bf16x8*)&Zb[0][zo];
        al[rf] = *(const bf16x8*)&Zb[1][zo];
      }
#pragma unroll
      for (int cf = 0; cf < 2; ++cf) {
        int n = wid * 32 + cf * 16 + l15;
        bf16x8 bh = *(const bf16x8*)&Wph[((size_t)((kkg * 4 + lq) * 512 + n)) * 8];
#pragma unroll
        for (int rf = 0; rf < 2; ++rf) {
          cs[rf][cf] = __builtin_amdgcn_mfma_f32_16x16x32_bf16(ah[rf], bh, cs[rf][cf], 0, 0, 0);
          cs[rf][cf] = __builtin_amdgcn_mfma_f32_16x16x32_bf16(al[rf], bh, cs[rf][cf], 0, 0, 0);
        }
      }
    }
  }
  __syncthreads();  // stage-1 reads done; Zb reusable

  // ---------- H LDS cache: copy first HC kk-slices (layout-identical) ----
  for (int i = tid * 8; i < HC * 16384; i += 8192)
    *(bf16x8*)&Hl2[i] = *(const bf16x8*)&Hh[i];

  // ---------- init: Z1 = ST(cs) -> Zb[0] ----------
#pragma unroll
  for (int rf = 0; rf < 2; ++rf)
#pragma unroll
    for (int cf = 0; cf < 2; ++cf) {
      int col = wid * 32 + cf * 16 + l15;
#pragma unroll
      for (int e = 0; e < 4; ++e) {
        float pre = cs[rf][cf][e];
        float mag = fmaxf(fabsf(pre) - thr, 0.f);
        float z = (pre >= 0.f) ? mag : -mag;
        int row = rf * 16 + lq * 4 + e;
        Zb[0][zswz(row, col)] = f2bf(z);
      }
    }
  __syncthreads();

  // ---------- iterations 1..49: Z[cur^1] = ST(Z[cur]*H + cs); 1 barrier ----
  int cur = 0;
#pragma unroll 1
  for (int it = 1; it < N_ITERS; ++it) {
    int rot = it & 15;
    f32x4 acc[2][2];
#pragma unroll
    for (int rf = 0; rf < 2; ++rf)
#pragma unroll
      for (int cf = 0; cf < 2; ++cf) acc[rf][cf] = cs[rf][cf];

#pragma unroll 2
    for (int kk = 0; kk < 16; ++kk) {
      int kkr = (kk + rot) & 15;  // it-dependent: defeats cross-iter LICM
      bf16x8 a[2];
#pragma unroll
      for (int rf = 0; rf < 2; ++rf)
        a[rf] = *(const bf16x8*)&Zb[cur][zoff8(rf * 16 + l15, kkr * 4 + lq)];
#pragma unroll
      for (int cf = 0; cf < 2; ++cf) {
        int n = wid * 32 + cf * 16 + l15;
        size_t off = ((size_t)((kkr * 4 + lq) * 512 + n)) * 8;
        bf16x8 bh;
        if (kkr < HC) bh = *(const bf16x8*)&Hl2[off];
        else bh = *(const bf16x8*)&Hh[off];
#pragma unroll
        for (int rf = 0; rf < 2; ++rf)
          acc[rf][cf] = __builtin_amdgcn_mfma_f32_16x16x32_bf16(a[rf], bh, acc[rf][cf], 0, 0, 0);
      }
    }
    // write other buffer: no conflict with concurrent reads of Zb[cur]
#pragma unroll
    for (int rf = 0; rf < 2; ++rf)
#pragma unroll
      for (int cf = 0; cf < 2; ++cf) {
        int col = wid * 32 + cf * 16 + l15;
#pragma unroll
        for (int e = 0; e < 4; ++e) {
          float pre = acc[rf][cf][e];
          float mag = fmaxf(fabsf(pre) - thr, 0.f);
          float z = (pre >= 0.f) ? mag : -mag;
          int row = rf * 16 + lq * 4 + e;
          Zb[cur ^ 1][zswz(row, col)] = f2bf(z);
        }
      }
    cur ^= 1;
    __syncthreads();
  }

  // ---------- sparsity count: scan final Z (swizzle is a bijection) ----------
  int cnt = 0;
#pragma unroll 4
  for (int i = tid; i < ROWS * ZSH; i += 1024)
    cnt += (fabsf(bf2f(Zb[cur][i])) > 1e-6f) ? 1 : 0;
#pragma unroll
  for (int off = 32; off; off >>= 1) cnt += __shfl_xor(cnt, off);
  if (lane == 0) atomicAdd(gcnt, cnt);

  // ---------- stage 3: out = Z * Wd^T (1024 cols = 16 waves x 64) ----------
  {
    f32x4 o[2][4];
#pragma unroll
    for (int rf = 0; rf < 2; ++rf)
#pragma unroll
      for (int cf = 0; cf < 4; ++cf) o[rf][cf] = (f32x4){0.f, 0.f, 0.f, 0.f};

#pragma unroll 2
    for (int kk = 0; kk < 16; ++kk) {
      bf16x8 a[2];
#pragma unroll
      for (int rf = 0; rf < 2; ++rf)
        a[rf] = *(const bf16x8*)&Zb[cur][zoff8(rf * 16 + l15, kk * 4 + lq)];
#pragma unroll
      for (int cf = 0; cf < 4; ++cf) {
        int n = wid * 64 + cf * 16 + l15;
        bf16x8 bh = *(const bf16x8*)&Wth[((size_t)((kk * 4 + lq) * 1024 + n)) * 8];
#pragma unroll
        for (int rf = 0; rf < 2; ++rf)
          o[rf][cf] = __builtin_amdgcn_mfma_f32_16x16x32_bf16(a[rf], bh, o[rf][cf], 0, 0, 0);
      }
    }
#pragma unroll
    for (int rf = 0; rf < 2; ++rf)
#pragma unroll
      for (int cf = 0; cf < 4; ++cf) {
        int col = wid * 64 + cf * 16 + l15;
#pragma unroll
        for (int e = 0; e < 4; ++e) {
          int row = rb + rf * 16 + lq * 4 + e;
          out[(size_t)row * DIM + col] = o[rf][cf][e];
        }
      }
  }
}

// ---------------- K5: finalize sparsity scalar ----------------
__global__ void k_final(const int* __restrict__ gcnt, float* __restrict__ out) {
  out[(size_t)BATCH * DIM] = (float)(*gcnt) / (float)BATCH;
}

extern "C" void kernel_launch(void* const* d_in, const int* in_sizes, int n_in,
                              void* d_out, int out_size, void* d_ws,
                              size_t ws_size, hipStream_t stream) {
  (void)in_sizes; (void)n_in; (void)out_size; (void)ws_size;
  const float* zex = (const float*)d_in[0];
  const float* Wd = (const float*)d_in[1];
  float* out = (float*)d_out;
  char* ws = (char*)d_ws;

  float* G = (float*)ws;                              // 1 MB @ 0
  float* G2 = (float*)(ws + (1 << 20));               // 1 MB @ 1M (scaled)
  float* G4 = (float*)(ws + 2 * (1 << 20));           // 1 MB @ 2M (scaled)
  float* G8 = (float*)(ws + 3 * (1 << 20));           // 1 MB @ 3M (scaled)
  short* Hh = (short*)(ws + 4 * (1 << 20));           // 512 KB @ 4M
  short* Wph = (short*)(ws + 4 * (1 << 20) + (512 << 10));  // 1 MB @ 4.5M
  short* Wth = (short*)(ws + 5 * (1 << 20) + (512 << 10));  // 1 MB @ 5.5M
  float* scal = (float*)(ws + 6 * (1 << 20) + (512 << 10)); // @ 6.5M
  int* gcnt = (int*)(ws + 6 * (1 << 20) + (512 << 10) + 64);

  hipMemsetAsync(gcnt, 0, sizeof(int), stream);
  dim3 gb(8, 8);
  // Power chain scaled by 2^-20 at the first squaring (R7 overflow fix).
  k_mmT<<<gb, 256, 0, stream>>>(Wd, Wd, G, DIM, 1.0f);          // G = Wd^T Wd
  k_mmT<<<gb, 256, 0, stream>>>(G, G, G2, KDIM, 9.5367431640625e-07f);  // G^2*2^-20
  k_mmT<<<gb, 256, 0, stream>>>(G2, G2, G4, KDIM, 1.0f);        // G^4*2^-40
  k_mmT<<<gb, 256, 0, stream>>>(G4, G4, G8, KDIM, 1.0f);        // G^8*2^-80
  k_power_fast<<<1, 1024, 0, stream>>>(G4, G8, G, scal);
  k_pack_h<<<1024, 256, 0, stream>>>(G, scal, Hh);
  k_pack_w<<<2048, 256, 0, stream>>>(Wd, scal, Wph);
  k_pack_wt<<<2048, 256, 0, stream>>>(Wd, Wth);
  k_ista<<<BATCH / ROWS, 1024, 0, stream>>>(zex, Hh, Wph, Wth, scal, out, gcnt);
  k_final<<<1, 1, 0, stream>>>(gcnt, out);
}

// Round 14
// 545.558 us; speedup vs baseline: 1.1209x; 1.1209x over previous
//
#include <hip/hip_runtime.h>
#include <math.h>

#define BATCH 8192
#define DIM 1024
#define KDIM 512
#define ALPHA_C 0.1f
#define N_ITERS 50
#define ROWS 32
#define ZSH 512
#define HC 3    // kk-slices of H cached in LDS (of 16); LDS = 64+96 = 160 KB
#define SEG 256 // K rows per split-K block

typedef short bf16x8 __attribute__((ext_vector_type(8)));
typedef float f32x4 __attribute__((ext_vector_type(4)));

__device__ __forceinline__ short f2bf(float x) {
  union { float f; unsigned u; } v; v.f = x;
  unsigned r = v.u + 0x7fffu + ((v.u >> 16) & 1u);
  return (short)(r >> 16);
}
__device__ __forceinline__ float bf2f(short s) {
  union { float f; unsigned u; } v;
  v.u = ((unsigned)(unsigned short)s) << 16;
  return v.f;
}

// XOR-swizzled LDS addressing (16B granule), key = row&15 (R13: kills the
// 4-way write conflict; SQ_LDS_BANK_CONFLICT 2.9e7 -> 5e5).
__device__ __forceinline__ int zswz(int row, int col) {
  return row * ZSH + ((((col >> 3) ^ (row & 15)) << 3) | (col & 7));
}
__device__ __forceinline__ int zoff8(int row, int colg) {
  return row * ZSH + ((colg ^ (row & 15)) << 3);
}

// ---------------- K1a: split-K partial C_z = A[z-seg]^T B[z-seg] ----------
// 32x32 tile, 2x2/thread, grid (16,16,K/SEG): 512-1024 blocks -> full chip
// (R13 regression: 64-block mmT used 1/4 chip, aux ballooned to 246 us).
__global__ __launch_bounds__(256) void k_mmT_part(const float* __restrict__ A,
                                                  const float* __restrict__ B,
                                                  float* __restrict__ P) {
  int tx = (threadIdx.x & 15) * 2;
  int ty = (threadIdx.x >> 4) * 2;
  int a0 = blockIdx.y * 32 + ty;
  int b0 = blockIdx.x * 32 + tx;
  int j0 = blockIdx.z * SEG;
  float a00 = 0.f, a01 = 0.f, a10 = 0.f, a11 = 0.f;
  for (int j = j0; j < j0 + SEG; j += 8) {
#pragma unroll
    for (int u = 0; u < 8; ++u) {
      float2 av = *(const float2*)&A[(size_t)(j + u) * KDIM + a0];
      float2 bv = *(const float2*)&B[(size_t)(j + u) * KDIM + b0];
      a00 += av.x * bv.x;
      a01 += av.x * bv.y;
      a10 += av.y * bv.x;
      a11 += av.y * bv.y;
    }
  }
  float* P0 = P + (size_t)blockIdx.z * KDIM * KDIM;
  *(float2*)&P0[(size_t)a0 * KDIM + b0] = make_float2(a00, a01);
  *(float2*)&P0[(size_t)(a0 + 1) * KDIM + b0] = make_float2(a10, a11);
}

// ---------------- K1b: C = scale * sum_z P_z (fixed order -> deterministic) -
__global__ __launch_bounds__(256) void k_red(const float* __restrict__ P,
                                             float* __restrict__ C, int S,
                                             float scale) {
  int t = blockIdx.x * 256 + threadIdx.x;  // 65536 float4 groups
  f32x4 s = (f32x4){0.f, 0.f, 0.f, 0.f};
  for (int z = 0; z < S; ++z) {
    f32x4 p = *(const f32x4*)&P[(size_t)z * KDIM * KDIM + t * 4];
    s.x += p.x; s.y += p.y; s.z += p.z; s.w += p.w;
  }
  s.x *= scale; s.y *= scale; s.z *= scale; s.w *= scale;
  *(f32x4*)&C[t * 4] = s;
}

// ---------------- K2: v = dir(G8s·G8s·G4s·1) == dir(G^20·1) (scales cancel);
// L = Rayleigh(G, v). Norm/Rayleigh accumulate in double (overflow-proof).
__global__ __launch_bounds__(1024) void k_power_fast(
    const float* __restrict__ G4, const float* __restrict__ G8,
    const float* __restrict__ G, float* __restrict__ scal) {
  __shared__ float v[KDIM];
  __shared__ float part[1024];
  __shared__ double red[16];
  __shared__ double red2[16];
  __shared__ float stot;
  int tid = threadIdx.x;
  int lane = tid & 63, wid = tid >> 6;
  int col = tid & 511, h = tid >> 9;
  if (h == 0) v[col] = 1.0f;
  __syncthreads();

  const float* mats[3] = {G4, G8, G8};
#pragma unroll
  for (int s = 0; s < 3; ++s) {
    const float* gp = mats[s] + (size_t)(h * 256) * KDIM + col;
    const float* vp = v + h * 256;
    float a0 = 0.f, a1 = 0.f, a2 = 0.f, a3 = 0.f;
#pragma unroll 4
    for (int j = 0; j < 256; j += 4) {
      a0 += gp[(size_t)(j + 0) * KDIM] * vp[j + 0];
      a1 += gp[(size_t)(j + 1) * KDIM] * vp[j + 1];
      a2 += gp[(size_t)(j + 2) * KDIM] * vp[j + 2];
      a3 += gp[(size_t)(j + 3) * KDIM] * vp[j + 3];
    }
    part[tid] = (a0 + a1) + (a2 + a3);
    __syncthreads();
    float u = 0.f;
    double ssq = 0.0;
    if (h == 0) {
      u = part[col] + part[col + 512];
      ssq = (double)u * (double)u;
    }
#pragma unroll
    for (int off = 32; off; off >>= 1) ssq += __shfl_xor(ssq, off);
    if (lane == 0) red[wid] = ssq;
    __syncthreads();
    if (tid == 0) {
      double t = 0.0;
      for (int i = 0; i < 16; ++i) t += red[i];
      stot = (float)(sqrt(t) + 1e-12);
    }
    __syncthreads();
    if (h == 0) v[col] = u / stot;
    __syncthreads();
  }

  // Rayleigh on fp32 G (unscaled)
  {
    const float* gp = G + (size_t)(h * 256) * KDIM + col;
    const float* vp = v + h * 256;
    float a0 = 0.f, a1 = 0.f, a2 = 0.f, a3 = 0.f;
#pragma unroll 4
    for (int j = 0; j < 256; j += 4) {
      a0 += gp[(size_t)(j + 0) * KDIM] * vp[j + 0];
      a1 += gp[(size_t)(j + 1) * KDIM] * vp[j + 1];
      a2 += gp[(size_t)(j + 2) * KDIM] * vp[j + 2];
      a3 += gp[(size_t)(j + 3) * KDIM] * vp[j + 3];
    }
    part[tid] = (a0 + a1) + (a2 + a3);
    __syncthreads();
    double nu = 0.0, de = 0.0;
    if (h == 0) {
      float u = part[col] + part[col + 512];
      nu = (double)v[col] * (double)u;
      de = (double)v[col] * (double)v[col];
    }
#pragma unroll
    for (int off = 32; off; off >>= 1) {
      nu += __shfl_xor(nu, off);
      de += __shfl_xor(de, off);
    }
    if (lane == 0) { red[wid] = nu; red2[wid] = de; }
    __syncthreads();
    if (tid == 0) {
      double n = 0.0, d = 0.0;
      for (int i = 0; i < 16; ++i) { n += red[i]; d += red2[i]; }
      float L = (float)(n / (d + 1e-12));
      float step = 1.0f / L;
      scal[0] = step;
      scal[1] = step * ALPHA_C;
    }
  }
}

// ---------------- K3: pack H = I - step*G (bf16 hi only, B-frag layout) ----
__global__ __launch_bounds__(256) void k_pack_h(const float* __restrict__ G,
                                                const float* __restrict__ scal,
                                                short* __restrict__ Hh) {
  int t = blockIdx.x * 256 + threadIdx.x;  // 512*512
  int k = t >> 9, n = t & 511;
  float step = scal[0];
  float h = ((k == n) ? 1.0f : 0.0f) - step * G[k * KDIM + n];
  int kk = k >> 5, q = (k >> 3) & 3, j = k & 7;
  Hh[((size_t)((kk * 4 + q) * 512 + n)) * 8 + j] = f2bf(h);
}

// Wph[((kk*4+q)*512 + n)*8 + j] = bf16(step*Wd[kk*32+q*8+j][n])
__global__ __launch_bounds__(256) void k_pack_w(const float* __restrict__ Wd,
                                                const float* __restrict__ scal,
                                                short* __restrict__ Wh) {
  int t = blockIdx.x * 256 + threadIdx.x;  // 1024*512
  int k = t >> 9, n = t & 511;
  float w = scal[0] * Wd[k * KDIM + n];
  int kk = k >> 5, q = (k >> 3) & 3, j = k & 7;
  Wh[((size_t)((kk * 4 + q) * 512 + n)) * 8 + j] = f2bf(w);
}

// Wth[((kk*4+q)*1024 + n)*8 + j] = bf16(Wd[n][kk*32+q*8+j])
__global__ __launch_bounds__(256) void k_pack_wt(const float* __restrict__ Wd,
                                                 short* __restrict__ Wh) {
  int t = blockIdx.x * 256 + threadIdx.x;  // 512*1024
  int k = t >> 10, n = t & 1023;
  float w = Wd[n * KDIM + k];
  int kk = k >> 5, q = (k >> 3) & 3, j = k & 7;
  Wh[((size_t)((kk * 4 + q) * 1024 + n)) * 8 + j] = f2bf(w);
}

// ---------------- K4: fused ISTA: 32 rows/block, 256 blocks, 16 waves ------
// R13 + (1) HC=3 (96 KB H in LDS, streams only 13/16 from L2), (2) stage-1
// hi-only (X-lo dropped: ~0.4% cs error, out err ~0.1 vs threshold 10.24),
// (3) kk=0 peeled so cs is the MFMA C-in (no acc-init movs).
// it-rotated kk defeats LICM hoist-and-spill (R4 pathology).
__global__ __launch_bounds__(1024) void k_ista(
    const float* __restrict__ zex, const short* __restrict__ Hh,
    const short* __restrict__ Wph, const short* __restrict__ Wth,
    const float* __restrict__ scal, float* __restrict__ out,
    int* __restrict__ gcnt) {
  __shared__ short Zb[2][ROWS * ZSH];  // 2 x 32 KB
  __shared__ short Hl2[HC * 16384];    // 96 KB: Hh[0 .. HC*16384)
  int tid = threadIdx.x;
  int lane = tid & 63, wid = tid >> 6;  // 16 waves, each 32 cols
  int l15 = lane & 15, lq = lane >> 4;
  int rb = blockIdx.x * ROWS;
  float thr = scal[1];

  // ---------- stage 1: cs = step * X * Wd  (X = permuted zex, hi only) ----
  f32x4 cs[2][2];
#pragma unroll
  for (int rf = 0; rf < 2; ++rf)
#pragma unroll
    for (int cf = 0; cf < 2; ++cf) cs[rf][cf] = (f32x4){0.f, 0.f, 0.f, 0.f};

  int sr = tid >> 5;         // row 0..31
  int sc = (tid & 31) >> 1;  // col-group 0..15
  int ph = tid & 1;          // m-phase 0..1
  for (int half = 0; half < 2; ++half) {
    __syncthreads();
    {
      const float* src =
          &zex[(size_t)(rb + sr) * DIM + sc * 64 + half * 32 + ph * 16];
#pragma unroll
      for (int m = 0; m < 16; m += 4) {
        float4 xv = *(const float4*)&src[m];
        float xs[4] = {xv.x, xv.y, xv.z, xv.w};
#pragma unroll
        for (int e = 0; e < 4; ++e) {
          int mm = ph * 16 + m + e;
          int dd = ((mm >> 3) << 7) + ((mm & 7) << 4) + sc;
          Zb[0][zswz(sr, dd)] = f2bf(xs[e]);
        }
      }
    }
    __syncthreads();
#pragma unroll 2
    for (int kk = 0; kk < 16; ++kk) {
      int kkg = half * 16 + kk;
      bf16x8 a[2];
#pragma unroll
      for (int rf = 0; rf < 2; ++rf)
        a[rf] = *(const bf16x8*)&Zb[0][zoff8(rf * 16 + l15, kk * 4 + lq)];
#pragma unroll
      for (int cf = 0; cf < 2; ++cf) {
        int n = wid * 32 + cf * 16 + l15;
        bf16x8 bh = *(const bf16x8*)&Wph[((size_t)((kkg * 4 + lq) * 512 + n)) * 8];
#pragma unroll
        for (int rf = 0; rf < 2; ++rf)
          cs[rf][cf] = __builtin_amdgcn_mfma_f32_16x16x32_bf16(a[rf], bh, cs[rf][cf], 0, 0, 0);
      }
    }
  }
  __syncthreads();  // stage-1 reads done; Zb reusable

  // ---------- H LDS cache: copy first HC kk-slices (layout-identical) ----
  for (int i = tid * 8; i < HC * 16384; i += 8192)
    *(bf16x8*)&Hl2[i] = *(const bf16x8*)&Hh[i];

  // ---------- init: Z1 = ST(cs) -> Zb[0] ----------
#pragma unroll
  for (int rf = 0; rf < 2; ++rf)
#pragma unroll
    for (int cf = 0; cf < 2; ++cf) {
      int col = wid * 32 + cf * 16 + l15;
#pragma unroll
      for (int e = 0; e < 4; ++e) {
        float pre = cs[rf][cf][e];
        float mag = fmaxf(fabsf(pre) - thr, 0.f);
        float z = (pre >= 0.f) ? mag : -mag;
        int row = rf * 16 + lq * 4 + e;
        Zb[0][zswz(row, col)] = f2bf(z);
      }
    }
  __syncthreads();

  // ---------- iterations 1..49: Z[cur^1] = ST(Z[cur]*H + cs); 1 barrier ----
  int cur = 0;
#pragma unroll 1
  for (int it = 1; it < N_ITERS; ++it) {
    int rot = it & 15;
    f32x4 acc[2][2];

    // peeled kk = 0: C-in = cs (saves 16 acc-init movs per iteration)
    {
      int kkr = rot;
      bf16x8 a[2];
#pragma unroll
      for (int rf = 0; rf < 2; ++rf)
        a[rf] = *(const bf16x8*)&Zb[cur][zoff8(rf * 16 + l15, kkr * 4 + lq)];
#pragma unroll
      for (int cf = 0; cf < 2; ++cf) {
        int n = wid * 32 + cf * 16 + l15;
        size_t off = ((size_t)((kkr * 4 + lq) * 512 + n)) * 8;
        bf16x8 bh = (kkr < HC) ? *(const bf16x8*)&Hl2[off]
                               : *(const bf16x8*)&Hh[off];
#pragma unroll
        for (int rf = 0; rf < 2; ++rf)
          acc[rf][cf] = __builtin_amdgcn_mfma_f32_16x16x32_bf16(a[rf], bh, cs[rf][cf], 0, 0, 0);
      }
    }
#pragma unroll 2
    for (int kk = 1; kk < 16; ++kk) {
      int kkr = (kk + rot) & 15;  // it-dependent: defeats cross-iter LICM
      bf16x8 a[2];
#pragma unroll
      for (int rf = 0; rf < 2; ++rf)
        a[rf] = *(const bf16x8*)&Zb[cur][zoff8(rf * 16 + l15, kkr * 4 + lq)];
#pragma unroll
      for (int cf = 0; cf < 2; ++cf) {
        int n = wid * 32 + cf * 16 + l15;
        size_t off = ((size_t)((kkr * 4 + lq) * 512 + n)) * 8;
        bf16x8 bh = (kkr < HC) ? *(const bf16x8*)&Hl2[off]
                               : *(const bf16x8*)&Hh[off];
#pragma unroll
        for (int rf = 0; rf < 2; ++rf)
          acc[rf][cf] = __builtin_amdgcn_mfma_f32_16x16x32_bf16(a[rf], bh, acc[rf][cf], 0, 0, 0);
      }
    }
    // write other buffer: no conflict with concurrent reads of Zb[cur]
#pragma unroll
    for (int rf = 0; rf < 2; ++rf)
#pragma unroll
      for (int cf = 0; cf < 2; ++cf) {
        int col = wid * 32 + cf * 16 + l15;
#pragma unroll
        for (int e = 0; e < 4; ++e) {
          float pre = acc[rf][cf][e];
          float mag = fmaxf(fabsf(pre) - thr, 0.f);
          float z = (pre >= 0.f) ? mag : -mag;
          int row = rf * 16 + lq * 4 + e;
          Zb[cur ^ 1][zswz(row, col)] = f2bf(z);
        }
      }
    cur ^= 1;
    __syncthreads();
  }

  // ---------- sparsity count: scan final Z (swizzle is a bijection) ----------
  int cnt = 0;
#pragma unroll 4
  for (int i = tid; i < ROWS * ZSH; i += 1024)
    cnt += (fabsf(bf2f(Zb[cur][i])) > 1e-6f) ? 1 : 0;
#pragma unroll
  for (int off = 32; off; off >>= 1) cnt += __shfl_xor(cnt, off);
  if (lane == 0) atomicAdd(gcnt, cnt);

  // ---------- stage 3: out = Z * Wd^T (1024 cols = 16 waves x 64) ----------
  {
    f32x4 o[2][4];
#pragma unroll
    for (int rf = 0; rf < 2; ++rf)
#pragma unroll
      for (int cf = 0; cf < 4; ++cf) o[rf][cf] = (f32x4){0.f, 0.f, 0.f, 0.f};

#pragma unroll 2
    for (int kk = 0; kk < 16; ++kk) {
      bf16x8 a[2];
#pragma unroll
      for (int rf = 0; rf < 2; ++rf)
        a[rf] = *(const bf16x8*)&Zb[cur][zoff8(rf * 16 + l15, kk * 4 + lq)];
#pragma unroll
      for (int cf = 0; cf < 4; ++cf) {
        int n = wid * 64 + cf * 16 + l15;
        bf16x8 bh = *(const bf16x8*)&Wth[((size_t)((kk * 4 + lq) * 1024 + n)) * 8];
#pragma unroll
        for (int rf = 0; rf < 2; ++rf)
          o[rf][cf] = __builtin_amdgcn_mfma_f32_16x16x32_bf16(a[rf], bh, o[rf][cf], 0, 0, 0);
      }
    }
#pragma unroll
    for (int rf = 0; rf < 2; ++rf)
#pragma unroll
      for (int cf = 0; cf < 4; ++cf) {
        int col = wid * 64 + cf * 16 + l15;
#pragma unroll
        for (int e = 0; e < 4; ++e) {
          int row = rb + rf * 16 + lq * 4 + e;
          out[(size_t)row * DIM + col] = o[rf][cf][e];
        }
      }
  }
}

// ---------------- K5: finalize sparsity scalar ----------------
__global__ void k_final(const int* __restrict__ gcnt, float* __restrict__ out) {
  out[(size_t)BATCH * DIM] = (float)(*gcnt) / (float)BATCH;
}

extern "C" void kernel_launch(void* const* d_in, const int* in_sizes, int n_in,
                              void* d_out, int out_size, void* d_ws,
                              size_t ws_size, hipStream_t stream) {
  (void)in_sizes; (void)n_in; (void)out_size; (void)ws_size;
  const float* zex = (const float*)d_in[0];
  const float* Wd = (const float*)d_in[1];
  float* out = (float*)d_out;
  char* ws = (char*)d_ws;

  float* G = (float*)ws;                              // 1 MB @ 0
  float* G2 = (float*)(ws + (1 << 20));               // 1 MB @ 1M (scaled)
  float* G4 = (float*)(ws + 2 * (1 << 20));           // 1 MB @ 2M (scaled)
  float* G8 = (float*)(ws + 3 * (1 << 20));           // 1 MB @ 3M (scaled)
  short* Hh = (short*)(ws + 4 * (1 << 20));           // 512 KB @ 4M
  short* Wph = (short*)(ws + 4 * (1 << 20) + (512 << 10));  // 1 MB @ 4.5M
  short* Wth = (short*)(ws + 5 * (1 << 20) + (512 << 10));  // 1 MB @ 5.5M
  float* scal = (float*)(ws + 6 * (1 << 20) + (512 << 10)); // @ 6.5M
  int* gcnt = (int*)(ws + 6 * (1 << 20) + (512 << 10) + 64);
  // split-K partial buffers live in regions that are (re)written LATER:
  float* PG = (float*)(ws + 1 * (1 << 20));   // 4 MB: covers G2,G4,G8,Hh,Wph-half
  float* PG2 = (float*)(ws + 2 * (1 << 20));  // 2 MB: covers G4,G8
  float* PG4 = (float*)(ws + 3 * (1 << 20));  // 2 MB: covers G8,Hh,Wph-half
  float* PG8 = (float*)(ws + 4 * (1 << 20));  // 2 MB: covers Hh,Wph,Wth-half

  hipMemsetAsync(gcnt, 0, sizeof(int), stream);
  // Power chain scaled by 2^-20 at the first squaring (R7 overflow fix).
  k_mmT_part<<<dim3(16, 16, 4), 256, 0, stream>>>(Wd, Wd, PG);
  k_red<<<256, 256, 0, stream>>>(PG, G, 4, 1.0f);                 // G = Wd^T Wd
  k_mmT_part<<<dim3(16, 16, 2), 256, 0, stream>>>(G, G, PG2);
  k_red<<<256, 256, 0, stream>>>(PG2, G2, 2, 9.5367431640625e-07f);  // G^2*2^-20
  k_mmT_part<<<dim3(16, 16, 2), 256, 0, stream>>>(G2, G2, PG4);
  k_red<<<256, 256, 0, stream>>>(PG4, G4, 2, 1.0f);               // G^4*2^-40
  k_mmT_part<<<dim3(16, 16, 2), 256, 0, stream>>>(G4, G4, PG8);
  k_red<<<256, 256, 0, stream>>>(PG8, G8, 2, 1.0f);               // G^8*2^-80
  k_power_fast<<<1, 1024, 0, stream>>>(G4, G8, G, scal);
  k_pack_h<<<1024, 256, 0, stream>>>(G, scal, Hh);
  k_pack_w<<<2048, 256, 0, stream>>>(Wd, scal, Wph);
  k_pack_wt<<<2048, 256, 0, stream>>>(Wd, Wth);
  k_ista<<<BATCH / ROWS, 1024, 0, stream>>>(zex, Hh, Wph, Wth, scal, out, gcnt);
  k_final<<<1, 1, 0, stream>>>(gcnt, out);
}

// Round 15
// 536.254 us; speedup vs baseline: 1.1403x; 1.0173x over previous
//
#include <hip/hip_runtime.h>
#include <math.h>

#define BATCH 8192
#define DIM 1024
#define KDIM 512
#define ALPHA_C 0.1f
#define N_ITERS 50
#define ROWS 32
#define ZSH 512
#define SEG 256
#define SH 32.0f   // H_off fp8 scale
#define SZ 16.0f   // Z fp8 scale
#define INVS 0.001953125f  // 1/(SH*SZ)

typedef short bf16x8 __attribute__((ext_vector_type(8)));
typedef float f32x4 __attribute__((ext_vector_type(4)));
typedef long longx2 __attribute__((ext_vector_type(2)));

__device__ __forceinline__ short f2bf(float x) {
  union { float f; unsigned u; } v; v.f = x;
  unsigned r = v.u + 0x7fffu + ((v.u >> 16) & 1u);
  return (short)(r >> 16);
}
__device__ __forceinline__ float bf2f(short s) {
  union { float f; unsigned u; } v;
  v.u = ((unsigned)(unsigned short)s) << 16;
  return v.f;
}

// bf16 LDS swizzle (16B granule, key row&15) — stage 1/3 buffer
__device__ __forceinline__ int zswz(int row, int col) {
  return row * ZSH + ((((col >> 3) ^ (row & 15)) << 3) | (col & 7));
}
__device__ __forceinline__ int zoff8(int row, int colg) {
  return row * ZSH + ((colg ^ (row & 15)) << 3);
}
// fp8 Z LDS addr: [row][lq][kk][j] bytes, granule-XOR key row&14 (even keys
// keep (kk,kk+1) b128 pairs in memory order).
__device__ __forceinline__ int z8a(int row, int c) {
  int g = ((((c >> 3) & 3) << 4) | (c >> 5)) ^ (row & 14);
  return row * 512 + g * 8 + (c & 7);
}

// ---------------- K1a: split-K partial C_z = A[z]^T B[z] ----------------
__global__ __launch_bounds__(256) void k_mmT_part(const float* __restrict__ A,
                                                  const float* __restrict__ B,
                                                  float* __restrict__ P) {
  int tx = (threadIdx.x & 15) * 2;
  int ty = (threadIdx.x >> 4) * 2;
  int a0 = blockIdx.y * 32 + ty;
  int b0 = blockIdx.x * 32 + tx;
  int j0 = blockIdx.z * SEG;
  float a00 = 0.f, a01 = 0.f, a10 = 0.f, a11 = 0.f;
  for (int j = j0; j < j0 + SEG; j += 8) {
#pragma unroll
    for (int u = 0; u < 8; ++u) {
      float2 av = *(const float2*)&A[(size_t)(j + u) * KDIM + a0];
      float2 bv = *(const float2*)&B[(size_t)(j + u) * KDIM + b0];
      a00 += av.x * bv.x;
      a01 += av.x * bv.y;
      a10 += av.y * bv.x;
      a11 += av.y * bv.y;
    }
  }
  float* P0 = P + (size_t)blockIdx.z * KDIM * KDIM;
  *(float2*)&P0[(size_t)a0 * KDIM + b0] = make_float2(a00, a01);
  *(float2*)&P0[(size_t)(a0 + 1) * KDIM + b0] = make_float2(a10, a11);
}

// ---------------- K1b: C = scale * sum_z P_z (deterministic) ---------------
__global__ __launch_bounds__(256) void k_red(const float* __restrict__ P,
                                             float* __restrict__ C, int S,
                                             float scale) {
  int t = blockIdx.x * 256 + threadIdx.x;
  f32x4 s = (f32x4){0.f, 0.f, 0.f, 0.f};
  for (int z = 0; z < S; ++z) {
    f32x4 p = *(const f32x4*)&P[(size_t)z * KDIM * KDIM + t * 4];
    s.x += p.x; s.y += p.y; s.z += p.z; s.w += p.w;
  }
  s.x *= scale; s.y *= scale; s.z *= scale; s.w *= scale;
  *(f32x4*)&C[t * 4] = s;
}

// ---------------- K2: v = dir(G8s·G8s·G4s·1) == dir(G^20·1); L = Rayleigh --
__global__ __launch_bounds__(1024) void k_power_fast(
    const float* __restrict__ G4, const float* __restrict__ G8,
    const float* __restrict__ G, float* __restrict__ scal) {
  __shared__ float v[KDIM];
  __shared__ float part[1024];
  __shared__ double red[16];
  __shared__ double red2[16];
  __shared__ float stot;
  int tid = threadIdx.x;
  int lane = tid & 63, wid = tid >> 6;
  int col = tid & 511, h = tid >> 9;
  if (h == 0) v[col] = 1.0f;
  __syncthreads();

  const float* mats[3] = {G4, G8, G8};
#pragma unroll
  for (int s = 0; s < 3; ++s) {
    const float* gp = mats[s] + (size_t)(h * 256) * KDIM + col;
    const float* vp = v + h * 256;
    float a0 = 0.f, a1 = 0.f, a2 = 0.f, a3 = 0.f;
#pragma unroll 4
    for (int j = 0; j < 256; j += 4) {
      a0 += gp[(size_t)(j + 0) * KDIM] * vp[j + 0];
      a1 += gp[(size_t)(j + 1) * KDIM] * vp[j + 1];
      a2 += gp[(size_t)(j + 2) * KDIM] * vp[j + 2];
      a3 += gp[(size_t)(j + 3) * KDIM] * vp[j + 3];
    }
    part[tid] = (a0 + a1) + (a2 + a3);
    __syncthreads();
    float u = 0.f;
    double ssq = 0.0;
    if (h == 0) {
      u = part[col] + part[col + 512];
      ssq = (double)u * (double)u;
    }
#pragma unroll
    for (int off = 32; off; off >>= 1) ssq += __shfl_xor(ssq, off);
    if (lane == 0) red[wid] = ssq;
    __syncthreads();
    if (tid == 0) {
      double t = 0.0;
      for (int i = 0; i < 16; ++i) t += red[i];
      stot = (float)(sqrt(t) + 1e-12);
    }
    __syncthreads();
    if (h == 0) v[col] = u / stot;
    __syncthreads();
  }

  {
    const float* gp = G + (size_t)(h * 256) * KDIM + col;
    const float* vp = v + h * 256;
    float a0 = 0.f, a1 = 0.f, a2 = 0.f, a3 = 0.f;
#pragma unroll 4
    for (int j = 0; j < 256; j += 4) {
      a0 += gp[(size_t)(j + 0) * KDIM] * vp[j + 0];
      a1 += gp[(size_t)(j + 1) * KDIM] * vp[j + 1];
      a2 += gp[(size_t)(j + 2) * KDIM] * vp[j + 2];
      a3 += gp[(size_t)(j + 3) * KDIM] * vp[j + 3];
    }
    part[tid] = (a0 + a1) + (a2 + a3);
    __syncthreads();
    double nu = 0.0, de = 0.0;
    if (h == 0) {
      float u = part[col] + part[col + 512];
      nu = (double)v[col] * (double)u;
      de = (double)v[col] * (double)v[col];
    }
#pragma unroll
    for (int off = 32; off; off >>= 1) {
      nu += __shfl_xor(nu, off);
      de += __shfl_xor(de, off);
    }
    if (lane == 0) { red[wid] = nu; red2[wid] = de; }
    __syncthreads();
    if (tid == 0) {
      double n = 0.0, d = 0.0;
      for (int i = 0; i < 16; ++i) { n += red[i]; d += red2[i]; }
      float L = (float)(n / (d + 1e-12));
      float step = 1.0f / L;
      scal[0] = step;
      scal[1] = step * ALPHA_C;
    }
  }
}

// ---------------- K3: pack H_off (fp8 e4m3, x32, zero diag) + hd (fp32) ----
// H8 byte layout: [(kk*4+lq)*4096 + n*8 + j] = fp8(SH * H_off[kk*32+lq*8+j][n])
__global__ __launch_bounds__(256) void k_pack_h8(const float* __restrict__ G,
                                                 const float* __restrict__ scal,
                                                 char* __restrict__ H8,
                                                 float* __restrict__ hd) {
  int t = blockIdx.x * 256 + threadIdx.x;  // 512*512
  int k = t >> 9, n = t & 511;
  float step = scal[0];
  float g = G[k * KDIM + n];
  if (k == n) hd[n] = 1.0f - step * g;
  float h = (k == n) ? 0.f : (-step * g) * SH;
  int p = __builtin_amdgcn_cvt_pk_fp8_f32(h, h, 0, false);
  size_t off = ((size_t)((k >> 5) * 4 + ((k >> 3) & 3))) * 4096 + n * 8 + (k & 7);
  H8[off] = (char)(p & 0xff);
}

// Wph (bf16 B-frag, step folded)
__global__ __launch_bounds__(256) void k_pack_w(const float* __restrict__ Wd,
                                                const float* __restrict__ scal,
                                                short* __restrict__ Wh) {
  int t = blockIdx.x * 256 + threadIdx.x;  // 1024*512
  int k = t >> 9, n = t & 511;
  float w = scal[0] * Wd[k * KDIM + n];
  int kk = k >> 5, q = (k >> 3) & 3, j = k & 7;
  Wh[((size_t)((kk * 4 + q) * 512 + n)) * 8 + j] = f2bf(w);
}

// Wth (bf16 B-frag of Wd^T)
__global__ __launch_bounds__(256) void k_pack_wt(const float* __restrict__ Wd,
                                                 short* __restrict__ Wh) {
  int t = blockIdx.x * 256 + threadIdx.x;  // 512*1024
  int k = t >> 10, n = t & 1023;
  float w = Wd[n * KDIM + k];
  int kk = k >> 5, q = (k >> 3) & 3, j = k & 7;
  Wh[((size_t)((kk * 4 + q) * 1024 + n)) * 8 + j] = f2bf(w);
}

// ---------------- K4: fused ISTA, fp8 off-diag + fp32-register diagonal ----
// Z fp8 (x16) dbuf in LDS (2x16 KB); H_off fp8 (x32) streamed from L2
// (256 KB/block/iter, halved); diag term exact: pre = cs + acc/512 +
// hd[col]*zreg (zreg = this thread's own Z elements, fp32 in VGPRs).
// Two linear kk segments (runtime trips: defeats LICM-spill; cheap addrs).
__global__ __launch_bounds__(1024) void k_ista(
    const float* __restrict__ zex, const char* __restrict__ H8,
    const float* __restrict__ hd, const short* __restrict__ Wph,
    const short* __restrict__ Wth, const float* __restrict__ scal,
    float* __restrict__ out, int* __restrict__ gcnt) {
  __shared__ short Xb[ROWS * ZSH];    // 32 KB bf16 (stage-1 X, stage-3 Z)
  __shared__ char Z8[2][ROWS * 512];  // 2 x 16 KB fp8 Z
  int tid = threadIdx.x;
  int lane = tid & 63, wid = tid >> 6;  // 16 waves, each 32 cols
  int l15 = lane & 15, lq = lane >> 4;
  int rb = blockIdx.x * ROWS;
  float thr = scal[1];

  // ---------- stage 1: cs = step * X * Wd  (bf16 hi, as R14) ----------
  f32x4 cs[2][2];
#pragma unroll
  for (int rf = 0; rf < 2; ++rf)
#pragma unroll
    for (int cf = 0; cf < 2; ++cf) cs[rf][cf] = (f32x4){0.f, 0.f, 0.f, 0.f};

  int sr = tid >> 5;
  int sc = (tid & 31) >> 1;
  int ph = tid & 1;
  for (int half = 0; half < 2; ++half) {
    __syncthreads();
    {
      const float* src =
          &zex[(size_t)(rb + sr) * DIM + sc * 64 + half * 32 + ph * 16];
#pragma unroll
      for (int m = 0; m < 16; m += 4) {
        float4 xv = *(const float4*)&src[m];
        float xs[4] = {xv.x, xv.y, xv.z, xv.w};
#pragma unroll
        for (int e = 0; e < 4; ++e) {
          int mm = ph * 16 + m + e;
          int dd = ((mm >> 3) << 7) + ((mm & 7) << 4) + sc;
          Xb[zswz(sr, dd)] = f2bf(xs[e]);
        }
      }
    }
    __syncthreads();
#pragma unroll 2
    for (int kk = 0; kk < 16; ++kk) {
      int kkg = half * 16 + kk;
      bf16x8 a[2];
#pragma unroll
      for (int rf = 0; rf < 2; ++rf)
        a[rf] = *(const bf16x8*)&Xb[zoff8(rf * 16 + l15, kk * 4 + lq)];
#pragma unroll
      for (int cf = 0; cf < 2; ++cf) {
        int n = wid * 32 + cf * 16 + l15;
        bf16x8 bh = *(const bf16x8*)&Wph[((size_t)((kkg * 4 + lq) * 512 + n)) * 8];
#pragma unroll
        for (int rf = 0; rf < 2; ++rf)
          cs[rf][cf] = __builtin_amdgcn_mfma_f32_16x16x32_bf16(a[rf], bh, cs[rf][cf], 0, 0, 0);
      }
    }
  }
  __syncthreads();

  // diag entries for this thread's two columns
  float hd0 = hd[wid * 32 + l15];
  float hd1 = hd[wid * 32 + 16 + l15];

  // ---------- init: Z1 = ST(cs) -> zreg (fp32) + Z8[0] (fp8 x16) ----------
  float zreg[2][2][4];
#pragma unroll
  for (int rf = 0; rf < 2; ++rf)
#pragma unroll
    for (int cf = 0; cf < 2; ++cf) {
      int col = wid * 32 + cf * 16 + l15;
#pragma unroll
      for (int e = 0; e < 4; ++e) {
        float pre = cs[rf][cf][e];
        float mag = fmaxf(fabsf(pre) - thr, 0.f);
        float z = (pre >= 0.f) ? mag : -mag;
        zreg[rf][cf][e] = z;
        int pk = __builtin_amdgcn_cvt_pk_fp8_f32(z * SZ, z * SZ, 0, false);
        Z8[0][z8a(rf * 16 + lq * 4 + e, col)] = (char)(pk & 0xff);
      }
    }
  __syncthreads();

  // per-lane invariant offsets
  int key = l15 & 14;
  int abase0 = l15 * 512 + lq * 128;
  int abase1 = (16 + l15) * 512 + lq * 128;
  int vb = lq * 4096 + (wid * 32 + l15) * 8;

  int cur = 0;
#pragma unroll 1
  for (int it = 1; it < N_ITERS; ++it) {
    f32x4 acc[2][2];
#pragma unroll
    for (int rf = 0; rf < 2; ++rf)
#pragma unroll
      for (int cf = 0; cf < 2; ++cf) acc[rf][cf] = (f32x4){0.f, 0.f, 0.f, 0.f};

    int ks = (it & 7) << 1;  // rotation start (even)
#define ISTA_BODY(kk)                                                         \
  {                                                                           \
    int ao = ((kk) ^ key) * 8;                                                \
    longx2 a0 = *(const longx2*)&Z8[cur][abase0 + ao];                        \
    longx2 a1 = *(const longx2*)&Z8[cur][abase1 + ao];                        \
    const char* hp = H8 + (size_t)(kk)*16384;                                 \
    long b00 = *(const long*)&hp[vb];                                         \
    long b01 = *(const long*)&hp[vb + 128];                                   \
    long b10 = *(const long*)&hp[vb + 16384];                                 \
    long b11 = *(const long*)&hp[vb + 16384 + 128];                           \
    acc[0][0] = __builtin_amdgcn_mfma_f32_16x16x32_fp8_fp8(a0.x, b00, acc[0][0], 0, 0, 0); \
    acc[1][0] = __builtin_amdgcn_mfma_f32_16x16x32_fp8_fp8(a1.x, b00, acc[1][0], 0, 0, 0); \
    acc[0][1] = __builtin_amdgcn_mfma_f32_16x16x32_fp8_fp8(a0.x, b01, acc[0][1], 0, 0, 0); \
    acc[1][1] = __builtin_amdgcn_mfma_f32_16x16x32_fp8_fp8(a1.x, b01, acc[1][1], 0, 0, 0); \
    acc[0][0] = __builtin_amdgcn_mfma_f32_16x16x32_fp8_fp8(a0.y, b10, acc[0][0], 0, 0, 0); \
    acc[1][0] = __builtin_amdgcn_mfma_f32_16x16x32_fp8_fp8(a1.y, b10, acc[1][0], 0, 0, 0); \
    acc[0][1] = __builtin_amdgcn_mfma_f32_16x16x32_fp8_fp8(a0.y, b11, acc[0][1], 0, 0, 0); \
    acc[1][1] = __builtin_amdgcn_mfma_f32_16x16x32_fp8_fp8(a1.y, b11, acc[1][1], 0, 0, 0); \
  }
#pragma unroll 1
    for (int kk = ks; kk < 16; kk += 2) ISTA_BODY(kk);
#pragma unroll 1
    for (int kk = 0; kk < ks; kk += 2) ISTA_BODY(kk);
#undef ISTA_BODY

    // update: pre = cs + acc/(SH*SZ) + hd[col]*zreg ; ST ; write fp8 to nxt
#pragma unroll
    for (int rf = 0; rf < 2; ++rf)
#pragma unroll
      for (int cf = 0; cf < 2; ++cf) {
        float hdc = cf ? hd1 : hd0;
        int col = wid * 32 + cf * 16 + l15;
#pragma unroll
        for (int e = 0; e < 4; ++e) {
          float pre = cs[rf][cf][e] + acc[rf][cf][e] * INVS +
                      hdc * zreg[rf][cf][e];
          float mag = fmaxf(fabsf(pre) - thr, 0.f);
          float z = (pre >= 0.f) ? mag : -mag;
          zreg[rf][cf][e] = z;
          int pk = __builtin_amdgcn_cvt_pk_fp8_f32(z * SZ, z * SZ, 0, false);
          Z8[cur ^ 1][z8a(rf * 16 + lq * 4 + e, col)] = (char)(pk & 0xff);
        }
      }
    cur ^= 1;
    __syncthreads();
  }

  // ---------- sparsity: exact count from fp32 zreg ----------
  int cnt = 0;
#pragma unroll
  for (int rf = 0; rf < 2; ++rf)
#pragma unroll
    for (int cf = 0; cf < 2; ++cf)
#pragma unroll
      for (int e = 0; e < 4; ++e)
        cnt += (fabsf(zreg[rf][cf][e]) > 1e-6f) ? 1 : 0;
#pragma unroll
  for (int off = 32; off; off >>= 1) cnt += __shfl_xor(cnt, off);
  if (lane == 0) atomicAdd(gcnt, cnt);

  // ---------- write final Z (fp32 regs) to Xb as bf16 for stage 3 ----------
#pragma unroll
  for (int rf = 0; rf < 2; ++rf)
#pragma unroll
    for (int cf = 0; cf < 2; ++cf) {
      int col = wid * 32 + cf * 16 + l15;
#pragma unroll
      for (int e = 0; e < 4; ++e)
        Xb[zswz(rf * 16 + lq * 4 + e, col)] = f2bf(zreg[rf][cf][e]);
    }
  __syncthreads();

  // ---------- stage 3: out = Z * Wd^T (1024 cols = 16 waves x 64) ----------
  {
    f32x4 o[2][4];
#pragma unroll
    for (int rf = 0; rf < 2; ++rf)
#pragma unroll
      for (int cf = 0; cf < 4; ++cf) o[rf][cf] = (f32x4){0.f, 0.f, 0.f, 0.f};

#pragma unroll 2
    for (int kk = 0; kk < 16; ++kk) {
      bf16x8 a[2];
#pragma unroll
      for (int rf = 0; rf < 2; ++rf)
        a[rf] = *(const bf16x8*)&Xb[zoff8(rf * 16 + l15, kk * 4 + lq)];
#pragma unroll
      for (int cf = 0; cf < 4; ++cf) {
        int n = wid * 64 + cf * 16 + l15;
        bf16x8 bh = *(const bf16x8*)&Wth[((size_t)((kk * 4 + lq) * 1024 + n)) * 8];
#pragma unroll
        for (int rf = 0; rf < 2; ++rf)
          o[rf][cf] = __builtin_amdgcn_mfma_f32_16x16x32_bf16(a[rf], bh, o[rf][cf], 0, 0, 0);
      }
    }
#pragma unroll
    for (int rf = 0; rf < 2; ++rf)
#pragma unroll
      for (int cf = 0; cf < 4; ++cf) {
        int col = wid * 64 + cf * 16 + l15;
#pragma unroll
        for (int e = 0; e < 4; ++e) {
          int row = rb + rf * 16 + lq * 4 + e;
          out[(size_t)row * DIM + col] = o[rf][cf][e];
        }
      }
  }
}

// ---------------- K5: finalize sparsity scalar ----------------
__global__ void k_final(const int* __restrict__ gcnt, float* __restrict__ out) {
  out[(size_t)BATCH * DIM] = (float)(*gcnt) / (float)BATCH;
}

extern "C" void kernel_launch(void* const* d_in, const int* in_sizes, int n_in,
                              void* d_out, int out_size, void* d_ws,
                              size_t ws_size, hipStream_t stream) {
  (void)in_sizes; (void)n_in; (void)out_size; (void)ws_size;
  const float* zex = (const float*)d_in[0];
  const float* Wd = (const float*)d_in[1];
  float* out = (float*)d_out;
  char* ws = (char*)d_ws;

  float* G = (float*)ws;                              // 1 MB @ 0
  float* G2 = (float*)(ws + (1 << 20));               // 1 MB @ 1M (scaled)
  float* G4 = (float*)(ws + 2 * (1 << 20));           // 1 MB @ 2M (scaled)
  float* G8 = (float*)(ws + 3 * (1 << 20));           // 1 MB @ 3M (scaled)
  char* H8 = (char*)(ws + 4 * (1 << 20));             // 256 KB @ 4M
  float* hd = (float*)(ws + 4 * (1 << 20) + (256 << 10));   // 2 KB @ 4.25M
  short* Wph = (short*)(ws + 4 * (1 << 20) + (512 << 10));  // 1 MB @ 4.5M
  short* Wth = (short*)(ws + 5 * (1 << 20) + (512 << 10));  // 1 MB @ 5.5M
  float* scal = (float*)(ws + 6 * (1 << 20) + (512 << 10)); // @ 6.5M
  int* gcnt = (int*)(ws + 6 * (1 << 20) + (512 << 10) + 64);
  // split-K partials: regions consumed before later tenants are written
  float* PG = (float*)(ws + 1 * (1 << 20));
  float* PG2 = (float*)(ws + 2 * (1 << 20));
  float* PG4 = (float*)(ws + 3 * (1 << 20));
  float* PG8 = (float*)(ws + 4 * (1 << 20));

  hipMemsetAsync(gcnt, 0, sizeof(int), stream);
  // Power chain scaled by 2^-20 at the first squaring (R7 overflow fix).
  k_mmT_part<<<dim3(16, 16, 4), 256, 0, stream>>>(Wd, Wd, PG);
  k_red<<<256, 256, 0, stream>>>(PG, G, 4, 1.0f);
  k_mmT_part<<<dim3(16, 16, 2), 256, 0, stream>>>(G, G, PG2);
  k_red<<<256, 256, 0, stream>>>(PG2, G2, 2, 9.5367431640625e-07f);
  k_mmT_part<<<dim3(16, 16, 2), 256, 0, stream>>>(G2, G2, PG4);
  k_red<<<256, 256, 0, stream>>>(PG4, G4, 2, 1.0f);
  k_mmT_part<<<dim3(16, 16, 2), 256, 0, stream>>>(G4, G4, PG8);
  k_red<<<256, 256, 0, stream>>>(PG8, G8, 2, 1.0f);
  k_power_fast<<<1, 1024, 0, stream>>>(G4, G8, G, scal);
  k_pack_h8<<<1024, 256, 0, stream>>>(G, scal, H8, hd);
  k_pack_w<<<2048, 256, 0, stream>>>(Wd, scal, Wph);
  k_pack_wt<<<2048, 256, 0, stream>>>(Wd, Wth);
  k_ista<<<BATCH / ROWS, 1024, 0, stream>>>(zex, H8, hd, Wph, Wth, scal, out,
                                            gcnt);
  k_final<<<1, 1, 0, stream>>>(gcnt, out);
}

// Round 16
// 457.477 us; speedup vs baseline: 1.3367x; 1.1722x over previous
//
#include <hip/hip_runtime.h>
#include <math.h>

#define BATCH 8192
#define DIM 1024
#define KDIM 512
#define ALPHA_C 0.1f
#define N_ITERS 50
#define ROWS 32
#define ZSH 512
#define SH 32.0f   // H_off fp8 scale
#define SZ 16.0f   // Z fp8 scale
#define INVS 0.001953125f  // 1/(SH*SZ)

typedef short bf16x8 __attribute__((ext_vector_type(8)));
typedef float f32x4 __attribute__((ext_vector_type(4)));
typedef long longx2 __attribute__((ext_vector_type(2)));

__device__ __forceinline__ short f2bf(float x) {
  union { float f; unsigned u; } v; v.f = x;
  unsigned r = v.u + 0x7fffu + ((v.u >> 16) & 1u);
  return (short)(r >> 16);
}
__device__ __forceinline__ float bf2f(short s) {
  union { float f; unsigned u; } v;
  v.u = ((unsigned)(unsigned short)s) << 16;
  return v.f;
}

// bf16 LDS swizzle (16B granule, key row&15)
__device__ __forceinline__ int zswz(int row, int col) {
  return row * ZSH + ((((col >> 3) ^ (row & 15)) << 3) | (col & 7));
}
__device__ __forceinline__ int zoff8(int row, int colg) {
  return row * ZSH + ((colg ^ (row & 15)) << 3);
}
// fp8 Z LDS addr (even XOR key keeps kk-pairs b128-contiguous)
__device__ __forceinline__ int z8a(int row, int c) {
  int g = ((((c >> 3) & 3) << 4) | (c >> 5)) ^ (row & 14);
  return row * 512 + g * 8 + (c & 7);
}

// ---------------- K1: pack Wd into bf16 B-frag layouts ---------------------
// Wbh[((kk*4+q)*512+n)*8+j] = bf16(Wd[kk*32+q*8+j][n])   (K=1024 frags)
//   -> serves Gram A AND B operands (C = B^T B) AND stage-1 B (step unfolded)
// Wth[((kk*4+q)*1024+n)*8+j] = bf16(Wd[n][kk*32+q*8+j])  (stage-3 B, K=512)
__global__ __launch_bounds__(256) void k_pack_wd(const float* __restrict__ Wd,
                                                 short* __restrict__ Wbh,
                                                 short* __restrict__ Wth) {
  int t = blockIdx.x * 256 + threadIdx.x;
  if (t < DIM * KDIM) {
    int k = t >> 9, n = t & 511;
    int kk = k >> 5, q = (k >> 3) & 3, j = k & 7;
    Wbh[((size_t)((kk * 4 + q) * 512 + n)) * 8 + j] = f2bf(Wd[(size_t)k * KDIM + n]);
  } else {
    int t2 = t - DIM * KDIM;
    int k = t2 >> 10, n = t2 & 1023;
    int kk = k >> 5, q = (k >> 3) & 3, j = k & 7;
    Wth[((size_t)((kk * 4 + q) * 1024 + n)) * 8 + j] = f2bf(Wd[(size_t)n * KDIM + k]);
  }
}

// ---------------- K2: symmetric GEMM on MFMA: C = scale * Af^T-form product -
// Af is a bf16 B-frag buffer; by symmetry it serves both operands.
// Outputs: optional fp32 row-major Cf32, optional bf16-frag Cbf.
// Grid: 32 blocks (one 16-row tile each) x 512 threads (8 waves x 64 cols).
__global__ __launch_bounds__(512) void k_gemm_sym(const short* __restrict__ Af,
                                                  int K, float scale,
                                                  float* __restrict__ Cf32,
                                                  short* __restrict__ Cbf) {
  int lane = threadIdx.x & 63, wid = threadIdx.x >> 6;
  int l15 = lane & 15, lq = lane >> 4;
  int rt = blockIdx.x;  // row tile 0..31
  f32x4 acc[4];
#pragma unroll
  for (int cf = 0; cf < 4; ++cf) acc[cf] = (f32x4){0.f, 0.f, 0.f, 0.f};
  int nk = K >> 5;
  for (int kk = 0; kk < nk; ++kk) {
    bf16x8 a = *(const bf16x8*)&Af[((size_t)((kk * 4 + lq) * 512 + rt * 16 + l15)) * 8];
#pragma unroll
    for (int cf = 0; cf < 4; ++cf) {
      bf16x8 b = *(const bf16x8*)&Af[((size_t)((kk * 4 + lq) * 512 + wid * 64 + cf * 16 + l15)) * 8];
      acc[cf] = __builtin_amdgcn_mfma_f32_16x16x32_bf16(a, b, acc[cf], 0, 0, 0);
    }
  }
#pragma unroll
  for (int cf = 0; cf < 4; ++cf) {
    int col = wid * 64 + cf * 16 + l15;
#pragma unroll
    for (int e = 0; e < 4; ++e) {
      int row = rt * 16 + lq * 4 + e;
      float v = acc[cf][e] * scale;
      if (Cf32) Cf32[(size_t)row * KDIM + col] = v;
      if (Cbf) {
        int kk = row >> 5, q = (row >> 3) & 3, j = row & 7;
        Cbf[((size_t)((kk * 4 + q) * 512 + col)) * 8 + j] = f2bf(v);
      }
    }
  }
}

// ---------------- K3: v = dir(G4^5 · 1) == dir(G^20 · 1); L = Rayleigh(G,v) -
__global__ __launch_bounds__(1024) void k_power_fast(
    const float* __restrict__ G4, const float* __restrict__ G,
    float* __restrict__ scal) {
  __shared__ float v[KDIM];
  __shared__ float part[1024];
  __shared__ double red[16];
  __shared__ double red2[16];
  __shared__ float stot;
  int tid = threadIdx.x;
  int lane = tid & 63, wid = tid >> 6;
  int col = tid & 511, h = tid >> 9;
  if (h == 0) v[col] = 1.0f;
  __syncthreads();

  for (int s = 0; s < 5; ++s) {
    const float* gp = G4 + (size_t)(h * 256) * KDIM + col;
    const float* vp = v + h * 256;
    float a0 = 0.f, a1 = 0.f, a2 = 0.f, a3 = 0.f;
#pragma unroll 4
    for (int j = 0; j < 256; j += 4) {
      a0 += gp[(size_t)(j + 0) * KDIM] * vp[j + 0];
      a1 += gp[(size_t)(j + 1) * KDIM] * vp[j + 1];
      a2 += gp[(size_t)(j + 2) * KDIM] * vp[j + 2];
      a3 += gp[(size_t)(j + 3) * KDIM] * vp[j + 3];
    }
    part[tid] = (a0 + a1) + (a2 + a3);
    __syncthreads();
    float u = 0.f;
    double ssq = 0.0;
    if (h == 0) {
      u = part[col] + part[col + 512];
      ssq = (double)u * (double)u;
    }
#pragma unroll
    for (int off = 32; off; off >>= 1) ssq += __shfl_xor(ssq, off);
    if (lane == 0) red[wid] = ssq;
    __syncthreads();
    if (tid == 0) {
      double t = 0.0;
      for (int i = 0; i < 16; ++i) t += red[i];
      stot = (float)(sqrt(t) + 1e-12);
    }
    __syncthreads();
    if (h == 0) v[col] = u / stot;
    __syncthreads();
  }

  // Rayleigh on fp32 G
  {
    const float* gp = G + (size_t)(h * 256) * KDIM + col;
    const float* vp = v + h * 256;
    float a0 = 0.f, a1 = 0.f, a2 = 0.f, a3 = 0.f;
#pragma unroll 4
    for (int j = 0; j < 256; j += 4) {
      a0 += gp[(size_t)(j + 0) * KDIM] * vp[j + 0];
      a1 += gp[(size_t)(j + 1) * KDIM] * vp[j + 1];
      a2 += gp[(size_t)(j + 2) * KDIM] * vp[j + 2];
      a3 += gp[(size_t)(j + 3) * KDIM] * vp[j + 3];
    }
    part[tid] = (a0 + a1) + (a2 + a3);
    __syncthreads();
    double nu = 0.0, de = 0.0;
    if (h == 0) {
      float u = part[col] + part[col + 512];
      nu = (double)v[col] * (double)u;
      de = (double)v[col] * (double)v[col];
    }
#pragma unroll
    for (int off = 32; off; off >>= 1) {
      nu += __shfl_xor(nu, off);
      de += __shfl_xor(de, off);
    }
    if (lane == 0) { red[wid] = nu; red2[wid] = de; }
    __syncthreads();
    if (tid == 0) {
      double n = 0.0, d = 0.0;
      for (int i = 0; i < 16; ++i) { n += red[i]; d += red2[i]; }
      float L = (float)(n / (d + 1e-12));
      float step = 1.0f / L;
      scal[0] = step;
      scal[1] = step * ALPHA_C;
    }
  }
}

// ---------------- K4: pack H_off (fp8 e4m3, x32, zero diag) + hd + gcnt=0 --
__global__ __launch_bounds__(256) void k_pack_h8(const float* __restrict__ G,
                                                 const float* __restrict__ scal,
                                                 char* __restrict__ H8,
                                                 float* __restrict__ hd,
                                                 int* __restrict__ gcnt) {
  int t = blockIdx.x * 256 + threadIdx.x;  // 512*512
  if (t == 0) *gcnt = 0;
  int k = t >> 9, n = t & 511;
  float step = scal[0];
  float g = G[(size_t)k * KDIM + n];
  if (k == n) hd[n] = 1.0f - step * g;
  float h = (k == n) ? 0.f : (-step * g) * SH;
  int p = __builtin_amdgcn_cvt_pk_fp8_f32(h, h, 0, false);
  size_t off = ((size_t)((k >> 5) * 4 + ((k >> 3) & 3))) * 4096 + n * 8 + (k & 7);
  H8[off] = (char)(p & 0xff);
}

// ---------------- K5: fused ISTA (identical to R15 except Wbh unscaled;
// cs *= step in registers after stage 1) ----------------------------------
__global__ __launch_bounds__(1024) void k_ista(
    const float* __restrict__ zex, const char* __restrict__ H8,
    const float* __restrict__ hd, const short* __restrict__ Wbh,
    const short* __restrict__ Wth, const float* __restrict__ scal,
    float* __restrict__ out, int* __restrict__ gcnt) {
  __shared__ short Xb[ROWS * ZSH];    // 32 KB bf16 (stage-1 X, stage-3 Z)
  __shared__ char Z8[2][ROWS * 512];  // 2 x 16 KB fp8 Z
  int tid = threadIdx.x;
  int lane = tid & 63, wid = tid >> 6;  // 16 waves, each 32 cols
  int l15 = lane & 15, lq = lane >> 4;
  int rb = blockIdx.x * ROWS;
  float thr = scal[1];

  // ---------- stage 1: cs = X * Wd (bf16 hi); scaled by step afterwards ----
  f32x4 cs[2][2];
#pragma unroll
  for (int rf = 0; rf < 2; ++rf)
#pragma unroll
    for (int cf = 0; cf < 2; ++cf) cs[rf][cf] = (f32x4){0.f, 0.f, 0.f, 0.f};

  int sr = tid >> 5;
  int sc = (tid & 31) >> 1;
  int ph = tid & 1;
  for (int half = 0; half < 2; ++half) {
    __syncthreads();
    {
      const float* src =
          &zex[(size_t)(rb + sr) * DIM + sc * 64 + half * 32 + ph * 16];
#pragma unroll
      for (int m = 0; m < 16; m += 4) {
        float4 xv = *(const float4*)&src[m];
        float xs[4] = {xv.x, xv.y, xv.z, xv.w};
#pragma unroll
        for (int e = 0; e < 4; ++e) {
          int mm = ph * 16 + m + e;
          int dd = ((mm >> 3) << 7) + ((mm & 7) << 4) + sc;
          Xb[zswz(sr, dd)] = f2bf(xs[e]);
        }
      }
    }
    __syncthreads();
#pragma unroll 2
    for (int kk = 0; kk < 16; ++kk) {
      int kkg = half * 16 + kk;
      bf16x8 a[2];
#pragma unroll
      for (int rf = 0; rf < 2; ++rf)
        a[rf] = *(const bf16x8*)&Xb[zoff8(rf * 16 + l15, kk * 4 + lq)];
#pragma unroll
      for (int cf = 0; cf < 2; ++cf) {
        int n = wid * 32 + cf * 16 + l15;
        bf16x8 bh = *(const bf16x8*)&Wbh[((size_t)((kkg * 4 + lq) * 512 + n)) * 8];
#pragma unroll
        for (int rf = 0; rf < 2; ++rf)
          cs[rf][cf] = __builtin_amdgcn_mfma_f32_16x16x32_bf16(a[rf], bh, cs[rf][cf], 0, 0, 0);
      }
    }
  }
  __syncthreads();

  // fold step into cs (Wbh is unscaled so it could double as the Gram operand)
  float step = scal[0];
#pragma unroll
  for (int rf = 0; rf < 2; ++rf)
#pragma unroll
    for (int cf = 0; cf < 2; ++cf) cs[rf][cf] *= step;

  float hd0 = hd[wid * 32 + l15];
  float hd1 = hd[wid * 32 + 16 + l15];

  // ---------- init: Z1 = ST(cs) -> zreg (fp32) + Z8[0] (fp8 x16) ----------
  float zreg[2][2][4];
#pragma unroll
  for (int rf = 0; rf < 2; ++rf)
#pragma unroll
    for (int cf = 0; cf < 2; ++cf) {
      int col = wid * 32 + cf * 16 + l15;
#pragma unroll
      for (int e = 0; e < 4; ++e) {
        float pre = cs[rf][cf][e];
        float mag = fmaxf(fabsf(pre) - thr, 0.f);
        float z = (pre >= 0.f) ? mag : -mag;
        zreg[rf][cf][e] = z;
        int pk = __builtin_amdgcn_cvt_pk_fp8_f32(z * SZ, z * SZ, 0, false);
        Z8[0][z8a(rf * 16 + lq * 4 + e, col)] = (char)(pk & 0xff);
      }
    }
  __syncthreads();

  int key = l15 & 14;
  int abase0 = l15 * 512 + lq * 128;
  int abase1 = (16 + l15) * 512 + lq * 128;
  int vb = lq * 4096 + (wid * 32 + l15) * 8;

  int cur = 0;
#pragma unroll 1
  for (int it = 1; it < N_ITERS; ++it) {
    f32x4 acc[2][2];
#pragma unroll
    for (int rf = 0; rf < 2; ++rf)
#pragma unroll
      for (int cf = 0; cf < 2; ++cf) acc[rf][cf] = (f32x4){0.f, 0.f, 0.f, 0.f};

    int ks = (it & 7) << 1;  // rotation start (even)
#define ISTA_BODY(kk)                                                         \
  {                                                                           \
    int ao = ((kk) ^ key) * 8;                                                \
    longx2 a0 = *(const longx2*)&Z8[cur][abase0 + ao];                        \
    longx2 a1 = *(const longx2*)&Z8[cur][abase1 + ao];                        \
    const char* hp = H8 + (size_t)(kk)*16384;                                 \
    long b00 = *(const long*)&hp[vb];                                         \
    long b01 = *(const long*)&hp[vb + 128];                                   \
    long b10 = *(const long*)&hp[vb + 16384];                                 \
    long b11 = *(const long*)&hp[vb + 16384 + 128];                           \
    acc[0][0] = __builtin_amdgcn_mfma_f32_16x16x32_fp8_fp8(a0.x, b00, acc[0][0], 0, 0, 0); \
    acc[1][0] = __builtin_amdgcn_mfma_f32_16x16x32_fp8_fp8(a1.x, b00, acc[1][0], 0, 0, 0); \
    acc[0][1] = __builtin_amdgcn_mfma_f32_16x16x32_fp8_fp8(a0.x, b01, acc[0][1], 0, 0, 0); \
    acc[1][1] = __builtin_amdgcn_mfma_f32_16x16x32_fp8_fp8(a1.x, b01, acc[1][1], 0, 0, 0); \
    acc[0][0] = __builtin_amdgcn_mfma_f32_16x16x32_fp8_fp8(a0.y, b10, acc[0][0], 0, 0, 0); \
    acc[1][0] = __builtin_amdgcn_mfma_f32_16x16x32_fp8_fp8(a1.y, b10, acc[1][0], 0, 0, 0); \
    acc[0][1] = __builtin_amdgcn_mfma_f32_16x16x32_fp8_fp8(a0.y, b11, acc[0][1], 0, 0, 0); \
    acc[1][1] = __builtin_amdgcn_mfma_f32_16x16x32_fp8_fp8(a1.y, b11, acc[1][1], 0, 0, 0); \
  }
#pragma unroll 1
    for (int kk = ks; kk < 16; kk += 2) ISTA_BODY(kk);
#pragma unroll 1
    for (int kk = 0; kk < ks; kk += 2) ISTA_BODY(kk);
#undef ISTA_BODY

#pragma unroll
    for (int rf = 0; rf < 2; ++rf)
#pragma unroll
      for (int cf = 0; cf < 2; ++cf) {
        float hdc = cf ? hd1 : hd0;
        int col = wid * 32 + cf * 16 + l15;
#pragma unroll
        for (int e = 0; e < 4; ++e) {
          float pre = cs[rf][cf][e] + acc[rf][cf][e] * INVS +
                      hdc * zreg[rf][cf][e];
          float mag = fmaxf(fabsf(pre) - thr, 0.f);
          float z = (pre >= 0.f) ? mag : -mag;
          zreg[rf][cf][e] = z;
          int pk = __builtin_amdgcn_cvt_pk_fp8_f32(z * SZ, z * SZ, 0, false);
          Z8[cur ^ 1][z8a(rf * 16 + lq * 4 + e, col)] = (char)(pk & 0xff);
        }
      }
    cur ^= 1;
    __syncthreads();
  }

  // ---------- sparsity: exact count from fp32 zreg ----------
  int cnt = 0;
#pragma unroll
  for (int rf = 0; rf < 2; ++rf)
#pragma unroll
    for (int cf = 0; cf < 2; ++cf)
#pragma unroll
      for (int e = 0; e < 4; ++e)
        cnt += (fabsf(zreg[rf][cf][e]) > 1e-6f) ? 1 : 0;
#pragma unroll
  for (int off = 32; off; off >>= 1) cnt += __shfl_xor(cnt, off);
  if (lane == 0) atomicAdd(gcnt, cnt);

  // ---------- write final Z (fp32 regs) to Xb as bf16 for stage 3 ----------
#pragma unroll
  for (int rf = 0; rf < 2; ++rf)
#pragma unroll
    for (int cf = 0; cf < 2; ++cf) {
      int col = wid * 32 + cf * 16 + l15;
#pragma unroll
      for (int e = 0; e < 4; ++e)
        Xb[zswz(rf * 16 + lq * 4 + e, col)] = f2bf(zreg[rf][cf][e]);
    }
  __syncthreads();

  // ---------- stage 3: out = Z * Wd^T (1024 cols = 16 waves x 64) ----------
  {
    f32x4 o[2][4];
#pragma unroll
    for (int rf = 0; rf < 2; ++rf)
#pragma unroll
      for (int cf = 0; cf < 4; ++cf) o[rf][cf] = (f32x4){0.f, 0.f, 0.f, 0.f};

#pragma unroll 2
    for (int kk = 0; kk < 16; ++kk) {
      bf16x8 a[2];
#pragma unroll
      for (int rf = 0; rf < 2; ++rf)
        a[rf] = *(const bf16x8*)&Xb[zoff8(rf * 16 + l15, kk * 4 + lq)];
#pragma unroll
      for (int cf = 0; cf < 4; ++cf) {
        int n = wid * 64 + cf * 16 + l15;
        bf16x8 bh = *(const bf16x8*)&Wth[((size_t)((kk * 4 + lq) * 1024 + n)) * 8];
#pragma unroll
        for (int rf = 0; rf < 2; ++rf)
          o[rf][cf] = __builtin_amdgcn_mfma_f32_16x16x32_bf16(a[rf], bh, o[rf][cf], 0, 0, 0);
      }
    }
#pragma unroll
    for (int rf = 0; rf < 2; ++rf)
#pragma unroll
      for (int cf = 0; cf < 4; ++cf) {
        int col = wid * 64 + cf * 16 + l15;
#pragma unroll
        for (int e = 0; e < 4; ++e) {
          int row = rb + rf * 16 + lq * 4 + e;
          out[(size_t)row * DIM + col] = o[rf][cf][e];
        }
      }
  }
}

// ---------------- K6: finalize sparsity scalar ----------------
__global__ void k_final(const int* __restrict__ gcnt, float* __restrict__ out) {
  out[(size_t)BATCH * DIM] = (float)(*gcnt) / (float)BATCH;
}

extern "C" void kernel_launch(void* const* d_in, const int* in_sizes, int n_in,
                              void* d_out, int out_size, void* d_ws,
                              size_t ws_size, hipStream_t stream) {
  (void)in_sizes; (void)n_in; (void)out_size; (void)ws_size;
  const float* zex = (const float*)d_in[0];
  const float* Wd = (const float*)d_in[1];
  float* out = (float*)d_out;
  char* ws = (char*)d_ws;

  float* G = (float*)ws;                                   // 1 MB   @ 0
  short* Gb = (short*)(ws + (1 << 20));                    // 512 KB @ 1M
  short* G2b = (short*)(ws + (1 << 20) + (512 << 10));     // 512 KB @ 1.5M
  float* G4 = (float*)(ws + 2 * (1 << 20));                // 1 MB   @ 2M
  char* H8 = (char*)(ws + 3 * (1 << 20));                  // 256 KB @ 3M
  float* hd = (float*)(ws + 3 * (1 << 20) + (256 << 10));  // 2 KB   @ 3.25M
  short* Wbh = (short*)(ws + 3 * (1 << 20) + (512 << 10)); // 1 MB   @ 3.5M
  short* Wth = (short*)(ws + 4 * (1 << 20) + (512 << 10)); // 1 MB   @ 4.5M
  float* scal = (float*)(ws + 5 * (1 << 20) + (512 << 10));// @ 5.5M
  int* gcnt = (int*)(ws + 5 * (1 << 20) + (512 << 10) + 64);

  // 8 dispatches total (was 14: split-K chain + memset eliminated)
  k_pack_wd<<<4096, 256, 0, stream>>>(Wd, Wbh, Wth);
  k_gemm_sym<<<32, 512, 0, stream>>>(Wbh, 1024, 1.0f, G, Gb);   // G = Wd^T Wd
  k_gemm_sym<<<32, 512, 0, stream>>>(Gb, 512, 9.5367431640625e-07f, nullptr, G2b);  // G^2 * 2^-20
  k_gemm_sym<<<32, 512, 0, stream>>>(G2b, 512, 1.0f, G4, nullptr);  // G^4 * 2^-40
  k_power_fast<<<1, 1024, 0, stream>>>(G4, G, scal);
  k_pack_h8<<<1024, 256, 0, stream>>>(G, scal, H8, hd, gcnt);
  k_ista<<<BATCH / ROWS, 1024, 0, stream>>>(zex, H8, hd, Wbh, Wth, scal, out,
                                            gcnt);
  k_final<<<1, 1, 0, stream>>>(gcnt, out);
}